// Round 6
// baseline (474.418 us; speedup 1.0000x reference)
//
#include <hip/hip_runtime.h>
#include <stdint.h>

#define N_ATOMS 500000
#define N_MOLS  25000
#define HID     300
#define BA      64        // atoms per block
#define WS_ELE  102400    // elements per repacked W matrix (20*10*64*8)
#define NCH     19        // K=16 chunks covering k<304 (chunk 19 is all pad)
#define SLAB    20480     // one K=16 B slab: [mtx:2][nt:10][lane:64][16B]

typedef __attribute__((ext_vector_type(8)))  short          short8v;
typedef __attribute__((ext_vector_type(16))) float          f32x16;

static __device__ __forceinline__ unsigned short f2bf(float f) {
  unsigned int u = __float_as_uint(f);
  u += 0x7fffu + ((u >> 16) & 1u);   // round-to-nearest-even
  return (unsigned short)(u >> 16);
}

static __device__ __forceinline__ short8v pack8(float4 a, float4 b) {
  short8v r;
  r[0] = (short)f2bf(a.x); r[1] = (short)f2bf(a.y);
  r[2] = (short)f2bf(a.z); r[3] = (short)f2bf(a.w);
  r[4] = (short)f2bf(b.x); r[5] = (short)f2bf(b.y);
  r[6] = (short)f2bf(b.z); r[7] = (short)f2bf(b.w);
  return r;
}

// Load 8 k-values (f32) from a row pointer; k0 in {0,8,...,296}; k>=300 pads 0.
static __device__ __forceinline__ void loadA(const float* hp, int k0,
                                             float4& f0, float4& f1) {
  if (k0 <= 288) {
    f0 = *reinterpret_cast<const float4*>(hp + k0);
    f1 = *reinterpret_cast<const float4*>(hp + k0 + 4);
  } else {                                   // k0 == 296
    f0 = *reinterpret_cast<const float4*>(hp + 296);
    f1 = make_float4(0.f, 0.f, 0.f, 0.f);
  }
}

// async global->LDS, 16B per lane; lds base wave-uniform.
static __device__ __forceinline__ void stage16(const char* gsrc, char* ldst, int ln) {
  __builtin_amdgcn_global_load_lds(
      (const __attribute__((address_space(1))) void*)(gsrc + ln * 16),
      (__attribute__((address_space(3))) void*)ldst, 16, 0, 0);
}

// ---------------------------------------------------------------------------
// Prep: repack W1/V1 into B-fragment order [kc16:20][nt:10][lane:64][j:8]
// (k = kc16*16 + (lane>>5)*8 + j, n = nt*32 + (lane&31)), pad biases/readout
// vectors to 320, zero the segment-sum accumulators.
// ---------------------------------------------------------------------------
__global__ void prep_kernel(
    const float* __restrict__ W1, const float* __restrict__ V1,
    const float* __restrict__ b1, const float* __restrict__ vb1,
    const float* __restrict__ W2, const float* __restrict__ V2,
    unsigned short* __restrict__ W1s, unsigned short* __restrict__ V1s,
    float* __restrict__ b1p, float* __restrict__ vb1p,
    float* __restrict__ W2p, float* __restrict__ V2p,
    float* __restrict__ sums)
{
  const int t = blockIdx.x * 256 + threadIdx.x;
  if (t < 2 * WS_ELE) {
    const float* src = (t < WS_ELE) ? W1 : V1;
    unsigned short* dst = (t < WS_ELE) ? W1s : V1s;
    const int i    = (t < WS_ELE) ? t : t - WS_ELE;
    const int j    = i & 7;
    const int lane = (i >> 3) & 63;
    const int nt   = (i >> 9) % 10;
    const int kc16 = i / 5120;
    const int k = kc16 * 16 + (lane >> 5) * 8 + j;
    const int n = nt * 32 + (lane & 31);
    const float v = (k < HID && n < HID) ? src[k * HID + n] : 0.f;
    dst[i] = f2bf(v);
  } else if (t < 2 * WS_ELE + 1280) {
    const int i = t - 2 * WS_ELE;
    const int which = i / 320;
    const int e = i - which * 320;
    const float* s = (which == 0) ? b1 : (which == 1) ? vb1 : (which == 2) ? W2 : V2;
    float*       d = (which == 0) ? b1p : (which == 1) ? vb1p : (which == 2) ? W2p : V2p;
    d[e] = (e < HID) ? s[e] : 0.f;
  } else if (t < 2 * WS_ELE + 1280 + 2 * N_MOLS) {
    sums[t - (2 * WS_ELE + 1280)] = 0.f;
  }
}

// ---------------------------------------------------------------------------
// Fused FFN x2. Block = 64 atoms, 512 threads, 8 waves =
// {mtx:2} x {ch:2} x {rg:2}: each wave owns 32 atoms x 160 cols of ONE matrix
// -> acc[5] f32x16 = 80 AGPR; total ~144 regs/wave -> ~14-16 waves/CU
// (2 blocks). B = K=16 slabs (20KB) double-buffered via global_load_lds
// (LDS 41.5KB -> 2 blocks/CU). A = depth-1 register prefetch (2 float4),
// issued FIRST each chunk, consumed next chunk -> HBM latency covered by a
// full chunk + the co-resident block. One barrier per chunk.
// ---------------------------------------------------------------------------
__global__ __launch_bounds__(512, 4) void fused_ffn(
    const float* __restrict__ hidden,
    const unsigned short* __restrict__ W1s, const unsigned short* __restrict__ V1s,
    const float* __restrict__ b1p, const float* __restrict__ vb1p,
    const float* __restrict__ W2p, const float* __restrict__ V2p,
    const float* __restrict__ b2, const float* __restrict__ vb2,
    float* __restrict__ outA, float* __restrict__ outW)
{
  __shared__ char lds[2 * SLAB];    // 40,960 B
  __shared__ float sOutA[BA];       // +256
  __shared__ float sOutW[BA];       // +256  -> 41,472 total

  const int tid = (int)threadIdx.x;
  const int ln  = tid & 63;
  const int wv  = tid >> 6;
  const int mtx = wv & 1;          // 0 = W-pass, 1 = V-pass
  const int ch  = (wv >> 1) & 1;   // col half (160 cols)
  const int rg  = wv >> 2;         // row group (32 atoms)
  const int l31 = ln & 31;
  const int lh  = ln >> 5;
  const long base = (long)blockIdx.x * BA;

  long rowl = base + rg * 32 + l31;
  if (rowl > N_ATOMS - 1) rowl = N_ATOMS - 1;   // clamp; results unused
  const float* hp = hidden + rowl * (long)HID;

  // B-staging role: wave wv stages pieces of each 20-piece slab
  // (waves 0-3: 3 pieces, waves 4-7: 2 pieces). Piece c: mtx=c/10, nt=c%10.
  const int p0 = (wv < 4) ? wv * 3 : 12 + (wv - 4) * 2;
  const int np = (wv < 4) ? 3 : 2;

  f32x16 acc[5] = {};

  // ---- prologue: A chunk 0 into regs (first!), B slab 0 into buf 0 ----
  float4 c0, c1;
  loadA(hp, lh * 8, c0, c1);
  #pragma unroll
  for (int r = 0; r < 3; ++r) {
    if (r < np) {
      const int c = p0 + r;
      const char* src = (c < 10) ? ((const char*)W1s + c * 1024)
                                 : ((const char*)V1s + (c - 10) * 1024);
      stage16(src, lds + c * 1024, ln);
    }
  }
  __syncthreads();   // slab 0 + A(0) ready

  // ---- main loop over 19 chunks of K=16 ----
  for (int c = 0; c < NCH; ++c) {
    const char* buf = lds + (c & 1) * SLAB;

    float4 n0, n1;
    if (c < NCH - 1) {
      // A loads for chunk c+1 first (deepest latency), then B stage
      loadA(hp, (c + 1) * 16 + lh * 8, n0, n1);
      char* nbuf = lds + ((c + 1) & 1) * SLAB;
      const char* wsrc = (const char*)W1s + (c + 1) * 10240;
      const char* vsrc = (const char*)V1s + (c + 1) * 10240;
      #pragma unroll
      for (int r = 0; r < 3; ++r) {
        if (r < np) {
          const int cc = p0 + r;
          const char* src = (cc < 10) ? (wsrc + cc * 1024) : (vsrc + (cc - 10) * 1024);
          stage16(src, nbuf + cc * 1024, ln);
        }
      }
    }

    // compute chunk c
    const short8v af = pack8(c0, c1);
    const char* bb = buf + mtx * 10240 + ch * 5120;
    #pragma unroll
    for (int nt = 0; nt < 5; ++nt) {
      const short8v bf = *reinterpret_cast<const short8v*>(bb + nt * 1024 + ln * 16);
      acc[nt] = __builtin_amdgcn_mfma_f32_32x32x16_bf16(af, bf, acc[nt], 0, 0, 0);
    }

    if (c < NCH - 1) { c0 = n0; c1 = n1; }
    __syncthreads();   // next slab staged; current free
  }

  // ---- epilogue: out[atom] = sum_n relu(X+b1)*W2 + b2 ----
  float bv[5], w2[5];
  const float* bbv = mtx ? vb1p : b1p;
  const float* ww2 = mtx ? V2p  : W2p;
  #pragma unroll
  for (int nt = 0; nt < 5; ++nt) {
    const int cix = ch * 160 + nt * 32 + l31;
    bv[nt] = bbv[cix];
    w2[nt] = ww2[cix];
  }
  if (tid < BA) { sOutA[tid] = 0.f; sOutW[tid] = 0.f; }
  __syncthreads();

  float* sOut = mtx ? sOutW : sOutA;
  #pragma unroll
  for (int r = 0; r < 16; ++r) {
    float s = 0.f;
    #pragma unroll
    for (int nt = 0; nt < 5; ++nt) {
      float x = fmaxf(acc[nt][r] + bv[nt], 0.f);
      s = fmaf(x, w2[nt], s);
    }
    s += __shfl_xor(s, 1);
    s += __shfl_xor(s, 2);
    s += __shfl_xor(s, 4);
    s += __shfl_xor(s, 8);
    s += __shfl_xor(s, 16);
    if (l31 == 0) {
      const int row = rg * 32 + (r & 3) + 8 * (r >> 2) + 4 * lh;
      atomicAdd(&sOut[row], s);
    }
  }
  __syncthreads();
  if (tid < BA) {
    const long atom = base + tid;
    if (atom < N_ATOMS) {
      outA[atom] = sOutA[tid] + b2[0];
      outW[atom] = sOutW[tid] + vb2[0];
    }
  }
}

// ---------------------------------------------------------------------------
// Segment sums: sorted seg_ids, run-compress 8 atoms/thread before atomics.
// ---------------------------------------------------------------------------
__global__ void segsum_kernel(
    const float* __restrict__ outA, const float* __restrict__ outW,
    const int* __restrict__ seg,
    float* __restrict__ sum_o, float* __restrict__ sum_w)
{
  const long i0 = ((long)blockIdx.x * 256 + threadIdx.x) * 8;
  if (i0 >= N_ATOMS) return;
  const int4   s0 = *reinterpret_cast<const int4*>(seg + i0);
  const int4   s1 = *reinterpret_cast<const int4*>(seg + i0 + 4);
  const float4 o0 = *reinterpret_cast<const float4*>(outA + i0);
  const float4 o1 = *reinterpret_cast<const float4*>(outA + i0 + 4);
  const float4 w0 = *reinterpret_cast<const float4*>(outW + i0);
  const float4 w1 = *reinterpret_cast<const float4*>(outW + i0 + 4);
  const int   ss[8] = {s0.x, s0.y, s0.z, s0.w, s1.x, s1.y, s1.z, s1.w};
  const float oo[8] = {o0.x, o0.y, o0.z, o0.w, o1.x, o1.y, o1.z, o1.w};
  const float ww[8] = {w0.x, w0.y, w0.z, w0.w, w1.x, w1.y, w1.z, w1.w};
  int cur = ss[0];
  float ao = 0.f, aw = 0.f;
  #pragma unroll
  for (int j = 0; j < 8; ++j) {
    if (ss[j] != cur) {
      atomicAdd(&sum_o[cur], ao);
      atomicAdd(&sum_w[cur], aw);
      cur = ss[j]; ao = 0.f; aw = 0.f;
    }
    ao += oo[j]; aw += ww[j];
  }
  atomicAdd(&sum_o[cur], ao);
  atomicAdd(&sum_w[cur], aw);
}

// ---------------------------------------------------------------------------
// Final: out = output + weights * (0 - sum_o[seg]) / sum_w'[seg]
// ---------------------------------------------------------------------------
__global__ void final_kernel(
    const float* __restrict__ outA, const float* __restrict__ outW,
    const int* __restrict__ seg,
    const float* __restrict__ sum_o, const float* __restrict__ sum_w,
    float* __restrict__ out)
{
  const long i0 = ((long)blockIdx.x * 256 + threadIdx.x) * 4;
  if (i0 >= N_ATOMS) return;
  const int4   s4 = *reinterpret_cast<const int4*>(seg + i0);
  const float4 o4 = *reinterpret_cast<const float4*>(outA + i0);
  const float4 w4 = *reinterpret_cast<const float4*>(outW + i0);
  const int   ss[4] = {s4.x, s4.y, s4.z, s4.w};
  const float oo[4] = {o4.x, o4.y, o4.z, o4.w};
  const float ww[4] = {w4.x, w4.y, w4.z, w4.w};
  float r[4];
  #pragma unroll
  for (int j = 0; j < 4; ++j) {
    const int s = ss[j];
    float sw = sum_w[s];
    sw = (sw == 0.f) ? 1.f : sw;
    const float corr = (0.f - sum_o[s]) / sw;
    r[j] = oo[j] + ww[j] * corr;
  }
  *reinterpret_cast<float4*>(out + i0) = make_float4(r[0], r[1], r[2], r[3]);
}

// ---------------------------------------------------------------------------
extern "C" void kernel_launch(void* const* d_in, const int* in_sizes, int n_in,
                              void* d_out, int out_size, void* d_ws, size_t ws_size,
                              hipStream_t stream)
{
  const float* hidden = (const float*)d_in[0];
  const int*   seg    = (const int*)d_in[1];
  const float* W1     = (const float*)d_in[2];
  const float* b1     = (const float*)d_in[3];
  const float* W2     = (const float*)d_in[4];
  const float* b2     = (const float*)d_in[5];
  const float* V1     = (const float*)d_in[6];
  const float* vb1    = (const float*)d_in[7];
  const float* V2     = (const float*)d_in[8];
  const float* vb2    = (const float*)d_in[9];

  char* ws = (char*)d_ws;
  float*          outA  = (float*)(ws + 0);          // 2,000,000 B
  float*          outW  = (float*)(ws + 2000000);    // 2,000,000 B
  float*          sum_o = (float*)(ws + 4000000);    //   100,000 B
  float*          sum_w = (float*)(ws + 4100000);    //   100,000 B
  unsigned short* W1s   = (unsigned short*)(ws + 4200000);  // 204,800 B
  unsigned short* V1s   = (unsigned short*)(ws + 4404800);  // 204,800 B
  float*          b1p   = (float*)(ws + 4609600);    // 1,280 B
  float*          vb1p  = (float*)(ws + 4610880);
  float*          W2p   = (float*)(ws + 4612160);
  float*          V2p   = (float*)(ws + 4613440);

  prep_kernel<<<1001, 256, 0, stream>>>(W1, V1, b1, vb1, W2, V2,
                                        W1s, V1s, b1p, vb1p, W2p, V2p, sum_o);

  const int nblk = (N_ATOMS + BA - 1) / BA;   // 7813
  fused_ffn<<<nblk, 512, 0, stream>>>(hidden, W1s, V1s, b1p, vb1p, W2p, V2p,
                                      b2, vb2, outA, outW);

  segsum_kernel<<<(N_ATOMS / 8 + 255) / 256, 256, 0, stream>>>(outA, outW, seg,
                                                               sum_o, sum_w);

  final_kernel<<<(N_ATOMS / 4 + 255) / 256, 256, 0, stream>>>(outA, outW, seg,
                                                              sum_o, sum_w,
                                                              (float*)d_out);
}